// Round 1
// baseline (416.235 us; speedup 1.0000x reference)
//
#include <hip/hip_runtime.h>
#include <hip/hip_bf16.h>

// Problem constants
// B=2, L=2048, NH=8, DH=64, DM=512. TEMP = 8.
// Outputs: qh (2,8,2048,64) fp32 then attn (2,8,2048,2048) fp32, concatenated.

typedef __attribute__((ext_vector_type(8))) short bf16x8_t;   // MFMA A/B frag (8 bf16)
typedef __attribute__((ext_vector_type(4))) float f32x4_t;    // MFMA C/D frag

#define MFMA16(a, b, c) __builtin_amdgcn_mfma_f32_16x16x32_bf16((a), (b), (c), 0, 0, 0)

__device__ __forceinline__ short f2bf(float x) {
    // round-to-nearest-even f32 -> bf16 (inputs are finite normals)
    union { float f; unsigned u; } v; v.f = x;
    unsigned r = v.u + 0x7fffu + ((v.u >> 16) & 1u);
    return (short)(r >> 16);
}

__device__ __forceinline__ bf16x8_t pack8(const float* p) {
    f32x4_t lo = *(const f32x4_t*)p;
    f32x4_t hi = *(const f32x4_t*)(p + 4);
    bf16x8_t r;
    r[0] = f2bf(lo[0]); r[1] = f2bf(lo[1]); r[2] = f2bf(lo[2]); r[3] = f2bf(lo[3]);
    r[4] = f2bf(hi[0]); r[5] = f2bf(hi[1]); r[6] = f2bf(hi[2]); r[7] = f2bf(hi[3]);
    return r;
}

// ---------------------------------------------------------------------------
// Kernel 1: C = A @ W^T for A in {q,k} (4096x512), W in {W_q,W_k} (512x512).
// grid (32, 4, 2): 128x128 tile per block; z selects q vs k.
// Epilogue permutes (m = b*2048+l, n = h*64+d) -> (b,h,l,d).
// z==0: writes fp32 qh to d_out AND bf16 qh to ws. z==1: bf16 kh to ws only.
// ---------------------------------------------------------------------------
__global__ __launch_bounds__(256) void proj_kernel(
    const float* __restrict__ q, const float* __restrict__ k,
    const float* __restrict__ Wq, const float* __restrict__ Wk,
    float* __restrict__ qh_f32, short* __restrict__ qh_bf,
    short* __restrict__ kh_bf)
{
    const int z  = blockIdx.z;
    const float* A = z ? k  : q;
    const float* W = z ? Wk : Wq;
    const int m0 = blockIdx.x * 128;
    const int n0 = blockIdx.y * 128;
    const int tid  = threadIdx.x;
    const int wave = tid >> 6;
    const int lane = tid & 63;
    const int wm = (wave >> 1) * 64;   // wave tile row (2x2 wave grid)
    const int wn = (wave & 1) * 64;    // wave tile col
    const int lrow = lane & 15;        // M (A) / N (B) index within 16
    const int lk   = (lane >> 4) * 8;  // K offset within 32 (quad*8)

    f32x4_t acc[4][4] = {};            // [mt][nt], 16x16 each -> wave 64x64

    for (int ks = 0; ks < 512; ks += 32) {
        bf16x8_t af[4], bfr[4];
#pragma unroll
        for (int mt = 0; mt < 4; ++mt) {
            const float* p = A + (size_t)(m0 + wm + mt * 16 + lrow) * 512 + ks + lk;
            af[mt] = pack8(p);
        }
#pragma unroll
        for (int nt = 0; nt < 4; ++nt) {
            const float* p = W + (size_t)(n0 + wn + nt * 16 + lrow) * 512 + ks + lk;
            bfr[nt] = pack8(p);
        }
#pragma unroll
        for (int mt = 0; mt < 4; ++mt)
#pragma unroll
            for (int nt = 0; nt < 4; ++nt)
                acc[mt][nt] = MFMA16(af[mt], bfr[nt], acc[mt][nt]);
    }

    // Epilogue. C layout (16x16x32): col = lane&15, row = (lane>>4)*4 + reg.
    const int g4 = (lane >> 4) * 4;
#pragma unroll
    for (int mt = 0; mt < 4; ++mt) {
#pragma unroll
        for (int r = 0; r < 4; ++r) {
            const int m  = m0 + wm + mt * 16 + g4 + r;
            const int bb = m >> 11;          // batch
            const int l  = m & 2047;         // seq pos
#pragma unroll
            for (int nt = 0; nt < 4; ++nt) {
                const int n = n0 + wn + nt * 16 + lrow;
                const int h = n >> 6;
                const int d = n & 63;
                const size_t idx = ((size_t)(bb * 8 + h) * 2048 + l) * 64 + d;
                const float v = acc[mt][nt][r];
                if (z == 0) {
                    qh_f32[idx] = v;
                    qh_bf[idx]  = f2bf(v);
                } else {
                    kh_bf[idx]  = f2bf(v);
                }
            }
        }
    }
}

// ---------------------------------------------------------------------------
// Kernel 2: attn = softmax over keys of (qh . kh / 8 + maskbias).
// grid (16, 32): blockIdx.x = b*8+h, blockIdx.y = 64-row q tile. 256 threads.
// Each wave owns 16 q rows; iterates all 2048 key cols in 16-col chunks.
// Pass 1: row sums of exp(s) (no max subtraction needed; |s| <~ 7).
// Pass 2: recompute, write exp(s)/sum.
// ---------------------------------------------------------------------------
__global__ __launch_bounds__(256) void attn_kernel(
    const short* __restrict__ qh, const short* __restrict__ kh,
    const int* __restrict__ mask, float* __restrict__ attn)
{
    const int bh = blockIdx.x;          // 0..15
    const int b  = bh >> 3;
    const int q0 = blockIdx.y * 64;
    const int tid = threadIdx.x;

    __shared__ float bias[2048];
    for (int j = tid; j < 2048; j += 256)
        bias[j] = mask[b * 2048 + j] ? 0.f : -1e9f;
    __syncthreads();

    const int wave = tid >> 6;
    const int lane = tid & 63;
    const int lrow = lane & 15;
    const int lk   = (lane >> 4) * 8;
    const int g4   = (lane >> 4) * 4;

    const short* Qb = qh + (size_t)bh * 2048 * 64;
    const short* Kb = kh + (size_t)bh * 2048 * 64;

    const int qrow = q0 + wave * 16 + lrow;
    const bf16x8_t qf0 = *(const bf16x8_t*)(Qb + (size_t)qrow * 64 + lk);
    const bf16x8_t qf1 = *(const bf16x8_t*)(Qb + (size_t)qrow * 64 + lk + 32);

    // ---- pass 1: row exp-sums ----
    float sum[4] = {0.f, 0.f, 0.f, 0.f};
#pragma unroll 4
    for (int kc = 0; kc < 2048; kc += 16) {
        const short* kp = Kb + (size_t)(kc + lrow) * 64 + lk;
        const bf16x8_t b0 = *(const bf16x8_t*)kp;
        const bf16x8_t b1 = *(const bf16x8_t*)(kp + 32);
        f32x4_t acc = {};
        acc = MFMA16(qf0, b0, acc);
        acc = MFMA16(qf1, b1, acc);
        const float bb = bias[kc + lrow];   // col = lane&15
#pragma unroll
        for (int r = 0; r < 4; ++r)
            sum[r] += __expf(acc[r] * 0.125f + bb);
    }
    // reduce across the 16 column lanes (xor 1,2,4,8 stays in-group)
#pragma unroll
    for (int m = 1; m < 16; m <<= 1) {
#pragma unroll
        for (int r = 0; r < 4; ++r)
            sum[r] += __shfl_xor(sum[r], m, 64);
    }
    float rinv[4];
#pragma unroll
    for (int r = 0; r < 4; ++r) rinv[r] = 1.f / sum[r];

    // ---- pass 2: recompute + write ----
    float* outb = attn + ((size_t)bh * 2048 + q0 + wave * 16 + g4) * 2048;
#pragma unroll 4
    for (int kc = 0; kc < 2048; kc += 16) {
        const short* kp = Kb + (size_t)(kc + lrow) * 64 + lk;
        const bf16x8_t b0 = *(const bf16x8_t*)kp;
        const bf16x8_t b1 = *(const bf16x8_t*)(kp + 32);
        f32x4_t acc = {};
        acc = MFMA16(qf0, b0, acc);
        acc = MFMA16(qf1, b1, acc);
        const float bb = bias[kc + lrow];
#pragma unroll
        for (int r = 0; r < 4; ++r)
            outb[(size_t)r * 2048 + kc + lrow] = __expf(acc[r] * 0.125f + bb) * rinv[r];
    }
}

// ---------------------------------------------------------------------------
extern "C" void kernel_launch(void* const* d_in, const int* in_sizes, int n_in,
                              void* d_out, int out_size, void* d_ws, size_t ws_size,
                              hipStream_t stream)
{
    const float* q    = (const float*)d_in[0];
    const float* k    = (const float*)d_in[1];
    const int*   mask = (const int*)  d_in[3];
    const float* Wq   = (const float*)d_in[4];
    const float* Wk   = (const float*)d_in[5];

    float* out    = (float*)d_out;
    float* qh_f32 = out;                 // 2*8*2048*64 = 2097152 floats
    float* attn   = out + 2097152;       // 2*8*2048*2048 floats

    short* qh_bf = (short*)d_ws;         // 4 MB
    short* kh_bf = qh_bf + 2097152;      // 4 MB

    proj_kernel<<<dim3(32, 4, 2), 256, 0, stream>>>(q, k, Wq, Wk, qh_f32, qh_bf, kh_bf);
    attn_kernel<<<dim3(16, 32), 256, 0, stream>>>(qh_bf, kh_bf, mask, attn);
}

// Round 2
// 385.154 us; speedup vs baseline: 1.0807x; 1.0807x over previous
//
#include <hip/hip_runtime.h>
#include <hip/hip_bf16.h>

// Problem constants: B=2, L=2048, NH=8, DH=64, DM=512, TEMP=8.
// Outputs (concat fp32): qh (2,8,2048,64) then attn (2,8,2048,2048).

typedef __attribute__((ext_vector_type(8))) short bf16x8_t;   // MFMA A/B frag
typedef __attribute__((ext_vector_type(4))) float f32x4_t;    // MFMA C/D frag
typedef __attribute__((ext_vector_type(4))) short s16x4_t;

#define MFMA16(a, b, c) __builtin_amdgcn_mfma_f32_16x16x32_bf16((a), (b), (c), 0, 0, 0)

__device__ __forceinline__ short f2bf(float x) {
    union { float f; unsigned u; } v; v.f = x;
    unsigned r = v.u + 0x7fffu + ((v.u >> 16) & 1u);
    return (short)(r >> 16);
}
__device__ __forceinline__ float bf2f(short x) {
    union { float f; unsigned u; } v;
    v.u = ((unsigned)(unsigned short)x) << 16;
    return v.f;
}

__device__ __forceinline__ bf16x8_t pack8(const float* p) {
    f32x4_t lo = *(const f32x4_t*)p;
    f32x4_t hi = *(const f32x4_t*)(p + 4);
    bf16x8_t r;
    r[0] = f2bf(lo[0]); r[1] = f2bf(lo[1]); r[2] = f2bf(lo[2]); r[3] = f2bf(lo[3]);
    r[4] = f2bf(hi[0]); r[5] = f2bf(hi[1]); r[6] = f2bf(hi[2]); r[7] = f2bf(hi[3]);
    return r;
}

// ---------------------------------------------------------------------------
// Kernel 1: C = A @ W^T for A in {q,k} (4096x512), W in {W_q,W_k} (512x512).
// grid (32, 4, 2): 128x128 tile per block; z selects q vs k.
// ---------------------------------------------------------------------------
__global__ __launch_bounds__(256) void proj_kernel(
    const float* __restrict__ q, const float* __restrict__ k,
    const float* __restrict__ Wq, const float* __restrict__ Wk,
    float* __restrict__ qh_f32, short* __restrict__ qh_bf,
    short* __restrict__ kh_bf)
{
    const int z  = blockIdx.z;
    const float* A = z ? k  : q;
    const float* W = z ? Wk : Wq;
    const int m0 = blockIdx.x * 128;
    const int n0 = blockIdx.y * 128;
    const int tid  = threadIdx.x;
    const int wave = tid >> 6;
    const int lane = tid & 63;
    const int wm = (wave >> 1) * 64;
    const int wn = (wave & 1) * 64;
    const int lrow = lane & 15;
    const int lk   = (lane >> 4) * 8;

    f32x4_t acc[4][4] = {};

    for (int ks = 0; ks < 512; ks += 32) {
        bf16x8_t af[4], bfr[4];
#pragma unroll
        for (int mt = 0; mt < 4; ++mt)
            af[mt] = pack8(A + (size_t)(m0 + wm + mt * 16 + lrow) * 512 + ks + lk);
#pragma unroll
        for (int nt = 0; nt < 4; ++nt)
            bfr[nt] = pack8(W + (size_t)(n0 + wn + nt * 16 + lrow) * 512 + ks + lk);
#pragma unroll
        for (int mt = 0; mt < 4; ++mt)
#pragma unroll
            for (int nt = 0; nt < 4; ++nt)
                acc[mt][nt] = MFMA16(af[mt], bfr[nt], acc[mt][nt]);
    }

    const int g4 = (lane >> 4) * 4;
#pragma unroll
    for (int mt = 0; mt < 4; ++mt) {
#pragma unroll
        for (int r = 0; r < 4; ++r) {
            const int m  = m0 + wm + mt * 16 + g4 + r;
            const int bb = m >> 11;
            const int l  = m & 2047;
#pragma unroll
            for (int nt = 0; nt < 4; ++nt) {
                const int n = n0 + wn + nt * 16 + lrow;
                const int h = n >> 6;
                const int d = n & 63;
                const size_t idx = ((size_t)(bb * 8 + h) * 2048 + l) * 64 + d;
                const float v = acc[mt][nt][r];
                if (z == 0) {
                    qh_f32[idx] = v;
                    qh_bf[idx]  = f2bf(v);
                } else {
                    kh_bf[idx]  = f2bf(v);
                }
            }
        }
    }
}

// ---------------------------------------------------------------------------
// Kernel 2 (single-pass): attn = softmax over keys of (qh.kh/8 + maskbias).
// grid (16, 128): x = b*8+h, y = 16-row q tile. 256 threads, 4 waves.
// Each wave handles a 512-key slice of the SAME 16 q rows; exp values staged
// in LDS as bf16 (padded stride 2052 -> 2-way max bank aliasing = free);
// fp32 row sums via xor-shuffle + LDS; coalesced float4 write phase.
// LDS ~74 KB -> 2 blocks/CU.
// ---------------------------------------------------------------------------
__global__ __launch_bounds__(256) void attn_kernel(
    const short* __restrict__ qh, const short* __restrict__ kh,
    const int* __restrict__ mask, float* __restrict__ attn)
{
    const int bh = blockIdx.x;          // 0..15
    const int b  = bh >> 3;
    const int q0 = blockIdx.y * 16;     // 0..2032
    const int tid = threadIdx.x;

    __shared__ short sc[16 * 2052];     // 65664 B: [row][key], stride 2052
    __shared__ float bias[2048];        // 8192 B
    __shared__ float psum[4 * 16];      // per-wave partial row sums
    __shared__ float rinv16[16];

    for (int j = tid; j < 2048; j += 256)
        bias[j] = mask[b * 2048 + j] ? 0.f : -1e9f;
    __syncthreads();

    const int wave = tid >> 6;
    const int lane = tid & 63;
    const int lrow = lane & 15;
    const int lk   = (lane >> 4) * 8;
    const int g4   = (lane >> 4) * 4;

    const short* Qb = qh + (size_t)bh * 2048 * 64;
    const short* Kb = kh + (size_t)bh * 2048 * 64;

    const int qrow = q0 + lrow;
    const bf16x8_t qf0 = *(const bf16x8_t*)(Qb + (size_t)qrow * 64 + lk);
    const bf16x8_t qf1 = *(const bf16x8_t*)(Qb + (size_t)qrow * 64 + lk + 32);

    // ---- score + exp phase: wave's 512-key slice ----
    float sum[4] = {0.f, 0.f, 0.f, 0.f};
    const int k0 = wave * 512;
#pragma unroll 4
    for (int kc = k0; kc < k0 + 512; kc += 16) {
        const short* kp = Kb + (size_t)(kc + lrow) * 64 + lk;
        const bf16x8_t b0 = *(const bf16x8_t*)kp;
        const bf16x8_t b1 = *(const bf16x8_t*)(kp + 32);
        f32x4_t acc = {};
        acc = MFMA16(qf0, b0, acc);
        acc = MFMA16(qf1, b1, acc);
        const float bb = bias[kc + lrow];   // col = lane&15
#pragma unroll
        for (int r = 0; r < 4; ++r) {
            const float e = __expf(acc[r] * 0.125f + bb);
            sum[r] += e;
            sc[(g4 + r) * 2052 + kc + lrow] = f2bf(e);
        }
    }
    // reduce across the 16 column lanes (xor 1,2,4,8 stays within group)
#pragma unroll
    for (int m = 1; m < 16; m <<= 1)
#pragma unroll
        for (int r = 0; r < 4; ++r)
            sum[r] += __shfl_xor(sum[r], m, 64);
    if (lrow == 0) {
#pragma unroll
        for (int r = 0; r < 4; ++r)
            psum[wave * 16 + g4 + r] = sum[r];
    }
    __syncthreads();
    if (tid < 16)
        rinv16[tid] = 1.f / (psum[tid] + psum[16 + tid] + psum[32 + tid] + psum[48 + tid]);
    __syncthreads();

    // ---- coalesced write phase: 16 rows x 2048 cols fp32 ----
    float* outb = attn + ((size_t)bh * 2048 + q0) * 2048;
    for (int i = tid; i < 16 * 512; i += 256) {
        const int row = i >> 9;
        const int c4  = (i & 511) << 2;
        const float rv = rinv16[row];
        const s16x4_t v = *(const s16x4_t*)(sc + row * 2052 + c4);
        f32x4_t o;
        o[0] = bf2f(v[0]) * rv;
        o[1] = bf2f(v[1]) * rv;
        o[2] = bf2f(v[2]) * rv;
        o[3] = bf2f(v[3]) * rv;
        *(f32x4_t*)(outb + (size_t)row * 2048 + c4) = o;
    }
}

// ---------------------------------------------------------------------------
extern "C" void kernel_launch(void* const* d_in, const int* in_sizes, int n_in,
                              void* d_out, int out_size, void* d_ws, size_t ws_size,
                              hipStream_t stream)
{
    const float* q    = (const float*)d_in[0];
    const float* k    = (const float*)d_in[1];
    const int*   mask = (const int*)  d_in[3];
    const float* Wq   = (const float*)d_in[4];
    const float* Wk   = (const float*)d_in[5];

    float* out    = (float*)d_out;
    float* qh_f32 = out;                 // 2,097,152 floats
    float* attn   = out + 2097152;       // 67,108,864 floats

    short* qh_bf = (short*)d_ws;         // 4 MB
    short* kh_bf = qh_bf + 2097152;      // 4 MB

    proj_kernel<<<dim3(32, 4, 2), 256, 0, stream>>>(q, k, Wq, Wk, qh_f32, qh_bf, kh_bf);
    attn_kernel<<<dim3(16, 128), 256, 0, stream>>>(qh_bf, kh_bf, mask, attn);
}